// Round 4
// baseline (786.485 us; speedup 1.0000x reference)
//
#include <hip/hip_runtime.h>
#include <hip/hip_bf16.h>
#include <cmath>

#define S_LEN 2048
#define E_DIM 512
#define B_SZ 4
#define CIN_D 64
#define COUT_D 64
#define L_NUM 4
#define CHK 256
#define NCHK 8
#define ROWS (B_SZ * S_LEN)  // 8192
#define PADR 2050            // padded rows per batch for causal conv
#define QLD 1024             // leading dim of fused qk buffer

typedef __attribute__((ext_vector_type(8))) short short8;
typedef __attribute__((ext_vector_type(4))) float f32x4;
typedef unsigned short ushort_t;

__device__ __forceinline__ ushort_t f2b(float v) {
  __hip_bfloat16 t = __float2bfloat16(v);
  return __builtin_bit_cast(ushort_t, t);
}
__device__ __forceinline__ float b2f(ushort_t u) {
  return __builtin_bit_cast(float, ((unsigned)u) << 16);
}

__device__ __forceinline__ void gload16(const void* g, void* l) {
  __builtin_amdgcn_global_load_lds((const __attribute__((address_space(1))) void*)g,
                                   (__attribute__((address_space(3))) void*)l, 16, 0, 0);
}

#define WAIT_BARRIER() asm volatile("s_waitcnt vmcnt(0)\ns_barrier" ::: "memory")

// ======================= universal bf16 MFMA GEMM =======================
// Tile TM x TN, BK=64, 4 waves (2x2), double-buffered LDS, 2-phase prefetch.
struct GemmP {
  const ushort_t* A; const ushort_t* B; const float* bias;
  float* Cf; ushort_t* Cb; const float* den;
  int nkt, lda, ldb, ldc;
  int aZrow, aZcol, bZrow, bZcol, cZrow;
  const ushort_t* A2; const ushort_t* B2;
  int nkt2, lda2, ldb2, a2Zrow, b2Zrow;
};

template <int TM, int TN, bool CONV>
__device__ __forceinline__ void mma_phase(const ushort_t* A, const ushort_t* B,
                                          int nkt, int lda, int ldb, int arow0,
                                          int acol0, int brow0, int bcol0,
                                          char* sm, int tid,
                                          f32x4 (&acc)[TM / 32][TN / 32]) {
  constexpr int MF = TM / 32, NF = TN / 32;
  constexpr int ABY = TM * 128, BBY = TN * 128, BUF = ABY + BBY;
  constexpr int RA = ABY / 4096, RB = BBY / 4096;
  const int lane = tid & 63, w = tid >> 6;
  const int wr = (w >> 1) * (TM / 2), wc = (w & 1) * (TN / 2);
  const int l15 = lane & 15, l4 = lane >> 4;

  auto stage = [&](int kt, int buf) {
    int ar0 = arow0, ac0 = acol0 + (kt << 6);
    if (CONV) {
      ar0 = arow0 + (kt >> 3);
      ac0 = acol0 + ((kt & 7) << 6);
    }
    char* s = sm + buf * BUF;
#pragma unroll
    for (int r = 0; r < RA; ++r) {
      const int f = (r << 12) + (tid << 4);
      const int row = f >> 7, sw = ((((f >> 4) & 7)) ^ (row & 7)) << 3;
      gload16(A + (size_t)(ar0 + row) * lda + ac0 + sw, s + f);
    }
    const int bc0 = bcol0 + (kt << 6);
#pragma unroll
    for (int r = 0; r < RB; ++r) {
      const int f = (r << 12) + (tid << 4);
      const int row = f >> 7, sw = ((((f >> 4) & 7)) ^ (row & 7)) << 3;
      gload16(B + (size_t)(brow0 + row) * ldb + bc0 + sw, s + ABY + f);
    }
  };

  stage(0, 0);
  WAIT_BARRIER();
  int cur = 0;
  for (int kt = 0; kt < nkt; ++kt) {
    if (kt + 1 < nkt) stage(kt + 1, cur ^ 1);  // prefetch next tile
    char* s = sm + cur * BUF;
#pragma unroll
    for (int kk = 0; kk < 2; ++kk) {
      short8 af[MF], bfv[NF];
#pragma unroll
      for (int m = 0; m < MF; ++m) {
        const int rt = wr + (m << 4) + l15;
        af[m] = *(const short8*)(s + rt * 128 +
                                 (((kk << 6) + (l4 << 4)) ^ ((rt & 7) << 4)));
      }
#pragma unroll
      for (int n = 0; n < NF; ++n) {
        const int rt = wc + (n << 4) + l15;
        bfv[n] = *(const short8*)(s + ABY + rt * 128 +
                                  (((kk << 6) + (l4 << 4)) ^ ((rt & 7) << 4)));
      }
#pragma unroll
      for (int m = 0; m < MF; ++m)
#pragma unroll
        for (int n = 0; n < NF; ++n)
          acc[m][n] = __builtin_amdgcn_mfma_f32_16x16x32_bf16(af[m], bfv[n],
                                                              acc[m][n], 0, 0, 0);
    }
    WAIT_BARRIER();
    cur ^= 1;
  }
}

// ACT: 0 none, 1 phi, 2 gelu, 3 phi-if-row<512 (fused k|v)
template <int TM, int TN, int ACT, bool READC, bool WRITEF, bool WRITEB,
          bool PADA, bool PADC, bool BIASROW, bool TRIMASK, bool SKIPUP,
          bool DIVDEN, bool TWOPH, bool CONV, bool SWZ>
__global__ __launch_bounds__(256) void gemm_mfma(GemmP p) {
  constexpr int MF = TM / 32, NF = TN / 32;
  __shared__ __align__(16) char smem[2 * (TM + TN) * 128];
  const int tid = threadIdx.x;
  int bxx = blockIdx.x, byy = blockIdx.y;
  if (SWZ) {  // XCD-aware remap: each XCD owns a contiguous slice of the
              // LARGER grid axis (nwg must be divisible by 8)
    const int gx = gridDim.x, gy = gridDim.y;
    const int hw = byy * gx + bxx;
    const int cpx = (gx * gy) >> 3;
    const int swz = (hw & 7) * cpx + (hw >> 3);
    if (gx >= gy) { bxx = swz / gy; byy = swz % gy; }
    else          { byy = swz / gx; bxx = swz % gx; }
  }
  const int bm = bxx * TM, bn = byy * TN, z = blockIdx.z;
  const int lane = tid & 63, w = tid >> 6;
  const int wr = (w >> 1) * (TM / 2), wc = (w & 1) * (TN / 2);
  const int l15 = lane & 15, l4 = lane >> 4;

  if (SKIPUP && bn >= bm + TM) {  // fully-masked tile: zero-fill Cb
#pragma unroll
    for (int m = 0; m < MF; ++m)
#pragma unroll
      for (int j = 0; j < 4; ++j) {
        const int rloc = bm + wr + (m << 4) + (l4 << 2) + j;
        const size_t crow = (size_t)p.cZrow * z + rloc;
#pragma unroll
        for (int n = 0; n < NF; ++n)
          p.Cb[crow * p.ldc + bn + wc + (n << 4) + l15] = 0;
      }
    return;
  }

  f32x4 acc[MF][NF];
#pragma unroll
  for (int m = 0; m < MF; ++m)
#pragma unroll
    for (int n = 0; n < NF; ++n)
#pragma unroll
      for (int j = 0; j < 4; ++j) acc[m][n][j] = 0.f;

  int arow0 = bm + p.aZrow * z;
  if (PADA) arow0 = bm + ((bm >> 11) << 1);  // padded batch base (tap in-phase)
  mma_phase<TM, TN, CONV>(p.A, p.B, p.nkt, p.lda, p.ldb, arow0, p.aZcol * z,
                          bn + p.bZrow * z, p.bZcol * z, smem, tid, acc);
  if (TWOPH)
    mma_phase<TM, TN, false>(p.A2, p.B2, p.nkt2, p.lda2, p.ldb2,
                             bm + p.a2Zrow * z, 0, bn + p.b2Zrow * z, 0, smem,
                             tid, acc);

  float bcol[NF];
  if (p.bias && !BIASROW) {
#pragma unroll
    for (int n = 0; n < NF; ++n) bcol[n] = p.bias[bn + wc + (n << 4) + l15];
  }
  int crow_base = bm;
  if (PADC) crow_base = bm + ((bm >> 11) << 1) + 2;
#pragma unroll
  for (int m = 0; m < MF; ++m) {
#pragma unroll
    for (int j = 0; j < 4; ++j) {
      const int rloc = wr + (m << 4) + (l4 << 2) + j;
      const size_t crow = (size_t)p.cZrow * z + crow_base + rloc;
      float inv = 1.f;
      if (DIVDEN) inv = 1.f / (p.den[crow] + 1e-6f);
      float brbias = 0.f;
      if (BIASROW && p.bias) brbias = p.bias[bm + rloc];
#pragma unroll
      for (int n = 0; n < NF; ++n) {
        const int col = bn + wc + (n << 4) + l15;
        float v = acc[m][n][j];
        if (p.bias) v += BIASROW ? brbias : bcol[n];
        if (ACT == 1) v = v > 0.f ? v + 1.f : __expf(v);
        if (ACT == 2) v = 0.5f * v * (1.f + erff(v * 0.70710678118654752f));
        if (ACT == 3 && (bm + rloc) < 512) v = v > 0.f ? v + 1.f : __expf(v);
        if (TRIMASK) {
          if (col > bm + rloc) v = 0.f;
        }
        const size_t cidx = crow * p.ldc + col;
        if (READC) v += p.Cf[cidx];
        if (DIVDEN) v *= inv;
        if (WRITEF) p.Cf[cidx] = v;
        if (WRITEB) p.Cb[cidx] = f2b(v);
      }
    }
  }
}

// ======================= prep / small kernels =======================

struct CvtP {
  const float *in_W, *cc_W, *Wq, *Wk, *Wv, *Wo, *c1W, *c2W, *bq, *bk, *bv;
  ushort_t *winb, *wconv, *wqkb, *wkvb, *wob, *wc1, *wc2;
  float *bqk, *bkv;
  ushort_t* t2pad;
};
__global__ void cvt_all(CvtP c) {
  const size_t NT = 32768 + 786432 + 2097152 * 2 + 1048576 * 3 + 4096 * 2 + 4096;
  for (size_t i = (size_t)blockIdx.x * 256 + threadIdx.x; i < NT;
       i += (size_t)gridDim.x * 256) {
    size_t j = i;
    if (j < 32768) { c.winb[j] = f2b(c.in_W[j]); continue; }
    j -= 32768;
    if (j < 786432) {  // wconv[n][tap*512+k] = cc_W[n][k][tap]
      size_t n = j / 1536, r = j % 1536;
      c.wconv[j] = f2b(c.cc_W[n * 1536 + (r & 511) * 3 + (r >> 9)]);
      continue;
    }
    j -= 786432;
    if (j < 2097152) {
      size_t l = j >> 19, r = j & 524287, row = r >> 9, k = r & 511;
      c.wqkb[j] = f2b(row < 512 ? c.Wq[l * 262144 + row * 512 + k]
                                : c.Wk[l * 262144 + (row - 512) * 512 + k]);
      continue;
    }
    j -= 2097152;
    if (j < 2097152) {
      size_t l = j >> 19, r = j & 524287, row = r >> 9, k = r & 511;
      c.wkvb[j] = f2b(row < 512 ? c.Wk[l * 262144 + row * 512 + k]
                                : c.Wv[l * 262144 + (row - 512) * 512 + k]);
      continue;
    }
    j -= 2097152;
    if (j < 1048576) { c.wob[j] = f2b(c.Wo[j]); continue; }
    j -= 1048576;
    if (j < 1048576) { c.wc1[j] = f2b(c.c1W[j]); continue; }
    j -= 1048576;
    if (j < 1048576) { c.wc2[j] = f2b(c.c2W[j]); continue; }
    j -= 1048576;
    if (j < 4096) {
      size_t l = j >> 10, r = j & 1023;
      c.bqk[j] = r < 512 ? c.bq[l * 512 + r] : c.bk[l * 512 + r - 512];
      continue;
    }
    j -= 4096;
    if (j < 4096) {
      size_t l = j >> 10, r = j & 1023;
      c.bkv[j] = r < 512 ? c.bk[l * 512 + r] : c.bv[l * 512 + r - 512];
      continue;
    }
    j -= 4096;
    {  // zero-fill the 2 pad rows at each batch start of t2pad
      int b = (int)(j >> 10), r = (int)(j & 1023);
      c.t2pad[(size_t)(b * PADR) * E_DIM + r] = 0;
    }
  }
}

__global__ __launch_bounds__(256) void transpose_x(const float* __restrict__ x,
                                                   ushort_t* __restrict__ xT) {
  __shared__ float t[64][65];
  const int b = blockIdx.z, s0 = blockIdx.x << 6, tid = threadIdx.x;
#pragma unroll
  for (int i = 0; i < 16; ++i) {
    int idx = tid + (i << 8);
    int c = idx >> 6, s = idx & 63;
    t[c][s] = x[(((size_t)(b * CIN_D + c)) << 11) + s0 + s];
  }
  __syncthreads();
#pragma unroll
  for (int i = 0; i < 16; ++i) {
    int idx = tid + (i << 8);
    int s = idx >> 6, c = idx & 63;
    xT[(((size_t)(b * S_LEN + s0 + s)) << 6) + c] = f2b(t[c][s]);
  }
}

// wave-per-row layernorm: 4 rows / block, no LDS, no barriers
__global__ __launch_bounds__(256) void layernorm_k(const float* __restrict__ x,
                                                   const float* __restrict__ g,
                                                   const float* __restrict__ bb,
                                                   ushort_t* __restrict__ y) {
  const int wid = threadIdx.x >> 6, lane = threadIdx.x & 63;
  const int row = (blockIdx.x << 2) + wid;
  const float* xr = x + ((size_t)row << 9);
  const float4 a = *(const float4*)(xr + (lane << 2));
  const float4 c = *(const float4*)(xr + 256 + (lane << 2));
  float s = a.x + a.y + a.z + a.w + c.x + c.y + c.z + c.w;
  float q2 = a.x * a.x + a.y * a.y + a.z * a.z + a.w * a.w + c.x * c.x +
             c.y * c.y + c.z * c.z + c.w * c.w;
#pragma unroll
  for (int off = 32; off; off >>= 1) {
    s += __shfl_xor(s, off);
    q2 += __shfl_xor(q2, off);
  }
  const float m = s * (1.f / 512.f);
  const float r = rsqrtf(q2 * (1.f / 512.f) - m * m + 1e-5f);
  const float4 g0 = *(const float4*)(g + (lane << 2));
  const float4 g1 = *(const float4*)(g + 256 + (lane << 2));
  const float4 b0 = *(const float4*)(bb + (lane << 2));
  const float4 b1 = *(const float4*)(bb + 256 + (lane << 2));
  uint2 w0, w1;
  w0.x = ((unsigned)f2b((a.y - m) * r * g0.y + b0.y) << 16) |
         f2b((a.x - m) * r * g0.x + b0.x);
  w0.y = ((unsigned)f2b((a.w - m) * r * g0.w + b0.w) << 16) |
         f2b((a.z - m) * r * g0.z + b0.z);
  w1.x = ((unsigned)f2b((c.y - m) * r * g1.y + b1.y) << 16) |
         f2b((c.x - m) * r * g1.x + b1.x);
  w1.y = ((unsigned)f2b((c.w - m) * r * g1.w + b1.w) << 16) |
         f2b((c.z - m) * r * g1.z + b1.z);
  ushort_t* yr = y + ((size_t)row << 9);
  *(uint2*)(yr + (lane << 2)) = w0;
  *(uint2*)(yr + 256 + (lane << 2)) = w1;
}

// ksum[z][e] = sum_t kT[e][z*256+t]; wave per (z,e), contiguous 8B loads
__global__ __launch_bounds__(256) void ksum_k(const ushort_t* __restrict__ kT,
                                              float* __restrict__ ks) {
  const int gw = (int)(((size_t)blockIdx.x << 8) + threadIdx.x) >> 6;
  const int lane = threadIdx.x & 63;
  const int z = gw >> 9, e = gw & 511;
  const uint2 u =
      *(const uint2*)(kT + (size_t)e * ROWS + (z << 8) + (lane << 2));
  float s = b2f(u.x & 0xffff) + b2f(u.x >> 16) + b2f(u.y & 0xffff) +
            b2f(u.y >> 16);
#pragma unroll
  for (int off = 32; off; off >>= 1) s += __shfl_xor(s, off);
  if (lane == 0) ks[(z << 9) + e] = s;
}

// merged: blocks 0..4095 = exclusive chunk prefix P->PTb (bf16);
//         blocks 4096..6143 = den (wave per row, ks prefix inlined)
__global__ __launch_bounds__(256) void misc_k(
    const float* __restrict__ P, ushort_t* __restrict__ PTb,
    const ushort_t* __restrict__ Sc, const ushort_t* __restrict__ qk,
    const float* __restrict__ ksum, float* __restrict__ den) {
  int bid = blockIdx.x;
  if (bid < 4096) {
    const size_t idx = ((size_t)bid << 8) + threadIdx.x;  // < B*E*E
    const int b = (int)(idx >> 18);
    const size_t r = idx & ((1u << 18) - 1);
    float acc = 0.f;
#pragma unroll
    for (int j = 0; j < NCHK; ++j) {
      const size_t o = (((size_t)(b * NCHK + j)) << 18) + r;
      PTb[o] = f2b(acc);
      acc += P[o];
    }
  } else {
    bid -= 4096;
    const int wid = threadIdx.x >> 6, lane = threadIdx.x & 63;
    const int row = (bid << 2) + wid;  // < 8192
    const int z = row >> 8, sl = row & 255;
    const ushort_t* sr = Sc + (((size_t)z) << 16) + ((size_t)sl << 8);
    float s = 0.f;
#pragma unroll
    for (int t = 0; t < 4; ++t) s += b2f(sr[lane + (t << 6)]);
    const ushort_t* qr = qk + (size_t)row * QLD;
    const int j0 = z & ~7;
    for (int e = lane; e < E_DIM; e += 64) {
      float kp = 0.f;
      for (int j = j0; j < z; ++j) kp += ksum[(j << 9) + e];
      s += b2f(qr[e]) * kp;
    }
#pragma unroll
    for (int off = 32; off; off >>= 1) s += __shfl_xor(s, off);
    if (lane == 0) den[row] = s;
  }
}

__global__ __launch_bounds__(256) void out_proj(const float* __restrict__ lat,
                                                const float* __restrict__ W,
                                                const float* __restrict__ bias,
                                                float* __restrict__ out) {
  const int b = blockIdx.z, bs = blockIdx.x << 6;
  const int tid = threadIdx.x, tm = tid >> 4, tn = tid & 15;
  const int lr = tid >> 2, lc = (tid & 3) << 2;
  __shared__ float As[16][64], Ws[16][64];
  float acc[4][4] = {{0.f}};
  for (int k0 = 0; k0 < E_DIM; k0 += 16) {
    float4 av =
        *(const float4*)(lat + (((size_t)(b * S_LEN + bs + lr)) << 9) + k0 + lc);
    As[lc + 0][lr] = av.x; As[lc + 1][lr] = av.y;
    As[lc + 2][lr] = av.z; As[lc + 3][lr] = av.w;
    float4 wv = *(const float4*)(W + (((size_t)lr) << 9) + k0 + lc);
    Ws[lc + 0][lr] = wv.x; Ws[lc + 1][lr] = wv.y;
    Ws[lc + 2][lr] = wv.z; Ws[lc + 3][lr] = wv.w;
    __syncthreads();
#pragma unroll
    for (int kk = 0; kk < 16; ++kk) {
      const float4 a4 = *(const float4*)&As[kk][tm << 2];
      const float4 b4 = *(const float4*)&Ws[kk][tn << 2];
      const float aa[4] = {a4.x, a4.y, a4.z, a4.w};
      const float bb[4] = {b4.x, b4.y, b4.z, b4.w};
#pragma unroll
      for (int i = 0; i < 4; ++i)
#pragma unroll
        for (int j2 = 0; j2 < 4; ++j2) acc[i][j2] += aa[i] * bb[j2];
    }
    __syncthreads();
  }
#pragma unroll
  for (int i = 0; i < 4; ++i)
#pragma unroll
    for (int j2 = 0; j2 < 4; ++j2) {
      const int o = (tn << 2) + j2, sl = bs + (tm << 2) + i;
      out[(((size_t)(b * COUT_D + o)) << 11) + sl] = acc[i][j2] + bias[o];
    }
}

// ======================= host launcher =======================
extern "C" void kernel_launch(void* const* d_in, const int* in_sizes, int n_in,
                              void* d_out, int out_size, void* d_ws,
                              size_t ws_size, hipStream_t stream) {
  const float* x = (const float*)d_in[0];
  const float* in_W = (const float*)d_in[1];
  const float* in_b = (const float*)d_in[2];
  const float* cc_W = (const float*)d_in[3];
  const float* cc_b = (const float*)d_in[4];
  const float* ln1g = (const float*)d_in[5];
  const float* ln1b = (const float*)d_in[6];
  const float* ln2g = (const float*)d_in[7];
  const float* ln2b = (const float*)d_in[8];
  const float* Wq = (const float*)d_in[9];
  const float* bq = (const float*)d_in[10];
  const float* Wk = (const float*)d_in[11];
  const float* bk = (const float*)d_in[12];
  const float* Wv = (const float*)d_in[13];
  const float* bv = (const float*)d_in[14];
  const float* Wo = (const float*)d_in[15];
  const float* bo = (const float*)d_in[16];
  const float* c1W = (const float*)d_in[17];
  const float* c1b = (const float*)d_in[18];
  const float* c2W = (const float*)d_in[19];
  const float* c2b = (const float*)d_in[20];
  const float* oW = (const float*)d_in[21];
  const float* ob = (const float*)d_in[22];
  float* out = (float*)d_out;

  const size_t NE = (size_t)ROWS * E_DIM;  // 4194304
  float* lat = (float*)d_ws;
  float* P = lat + NE;       // 8388608 f32
  float* ks = P + 8388608;   // 16384
  float* den = ks + 16384;   // 8192
  float* bqk = den + 8192;   // 4096
  float* bkv = bqk + 4096;   // 4096
  ushort_t* u = (ushort_t*)(bkv + 4096);
  ushort_t* xT = u;     u += (size_t)ROWS * CIN_D;
  ushort_t* t2pad = u;  u += (size_t)B_SZ * PADR * E_DIM;
  ushort_t* h = u;      u += NE;
  ushort_t* qk = u;     u += (size_t)ROWS * QLD;
  ushort_t* kvT = u;    u += (size_t)1024 * ROWS;
  ushort_t* PTb = u;    u += 8388608;
  ushort_t* t2b = u;    u += NE;
  ushort_t* winb = u;   u += 32768;
  ushort_t* wconv = u;  u += 786432;
  ushort_t* wqkb = u;   u += 2097152;
  ushort_t* wkvb = u;   u += 2097152;
  ushort_t* wob = u;    u += 1048576;
  ushort_t* wc1 = u;    u += 1048576;
  ushort_t* wc2 = u;    u += 1048576;
  ushort_t* Sc = t2pad;  // alias: t2pad dead after conv; 2M <= 4.2M elems
  ushort_t* kT = kvT;    // rows 0..511
  ushort_t* vT = kvT + (size_t)512 * ROWS;

  const dim3 blk(256);

  CvtP cp{in_W, cc_W, Wq, Wk, Wv, Wo, c1W, c2W, bq, bk, bv,
          winb, wconv, wqkb, wkvb, wob, wc1, wc2, bqk, bkv, t2pad};
  cvt_all<<<dim3(4096), blk, 0, stream>>>(cp);
  transpose_x<<<dim3(S_LEN / 64, 1, B_SZ), blk, 0, stream>>>(x, xT);

  GemmP p;
  auto clr = [&]() {
    p = GemmP{};
    p.lda = E_DIM; p.ldb = E_DIM; p.ldc = E_DIM;
  };

  // input projection -> padded bf16 latent (K=64)
  clr(); p.A = xT; p.B = winb; p.bias = in_b; p.Cb = t2pad;
  p.nkt = 1; p.lda = 64; p.ldb = 64;
  gemm_mfma<128,128,0,0,0,1,0,1,0,0,0,0,0,0,1><<<dim3(64,4), blk, 0, stream>>>(p);
  // fused causal conv: one GEMM, K=1536 (3 taps x 512)
  clr(); p.A = t2pad; p.B = wconv; p.bias = cc_b; p.Cf = lat;
  p.nkt = 24; p.ldb = 1536;
  gemm_mfma<128,128,0,0,1,0,1,0,0,0,0,0,0,1,1><<<dim3(64,4), blk, 0, stream>>>(p);

  for (int i = 0; i < L_NUM; ++i) {
    const size_t wOff = (size_t)i * E_DIM * E_DIM;
    const size_t bOff = (size_t)i * E_DIM;
    layernorm_k<<<dim3(ROWS / 4), blk, 0, stream>>>(lat, ln1g + bOff,
                                                    ln1b + bOff, h);
    // fused q|k (phi on both): [8192 x 1024]
    clr(); p.A = h; p.B = wqkb + (size_t)i * 524288; p.bias = bqk + i * 1024;
    p.Cb = qk; p.nkt = 8; p.ldc = QLD;
    gemm_mfma<128,128,1,0,0,1,0,0,0,0,0,0,0,0,1><<<dim3(64,8), blk, 0, stream>>>(p);
    // fused kT|vT (phi on k rows only): [1024 x 8192]
    clr(); p.A = wkvb + (size_t)i * 524288; p.B = h; p.bias = bkv + i * 1024;
    p.Cb = kvT; p.nkt = 8; p.ldc = ROWS;
    gemm_mfma<128,128,3,0,0,1,0,0,1,0,0,0,0,0,1><<<dim3(8,64), blk, 0, stream>>>(p);
    ksum_k<<<dim3(4096), blk, 0, stream>>>(kT, ks);
    // per-chunk PT[e'][e] = sum_t vT[e',t] kT[e,t]
    clr(); p.A = vT; p.B = kT; p.Cf = P; p.nkt = 4;
    p.lda = ROWS; p.ldb = ROWS; p.aZcol = CHK; p.bZcol = CHK; p.cZrow = E_DIM;
    gemm_mfma<128,128,0,0,1,0,0,0,0,0,0,0,0,0,0><<<dim3(4,4,B_SZ*NCHK), blk, 0, stream>>>(p);
    // intra-chunk masked scores -> Sc (bf16, aliased onto t2pad)
    clr(); p.A = qk; p.B = qk + 512; p.Cb = Sc; p.nkt = 8;
    p.lda = QLD; p.ldb = QLD; p.ldc = CHK;
    p.aZrow = CHK; p.bZrow = CHK; p.cZrow = CHK;
    gemm_mfma<128,64,0,0,0,1,0,0,0,1,1,0,0,0,0><<<dim3(2,4,B_SZ*NCHK), blk, 0, stream>>>(p);
    // merged: prefix_kv (P->PTb) || den (rowsum(Sc) + q . inline-ks-prefix)
    misc_k<<<dim3(6144), blk, 0, stream>>>(P, PTb, Sc, qk, ks, den);
    // combine: (Sc@vT + q@PTb) / den -> t2b (bf16)
    clr(); p.A = Sc; p.B = vT; p.Cb = t2b; p.den = den;
    p.nkt = 4; p.lda = CHK; p.ldb = ROWS; p.aZrow = CHK; p.bZcol = CHK; p.cZrow = CHK;
    p.A2 = qk; p.B2 = PTb; p.nkt2 = 8; p.lda2 = QLD; p.ldb2 = E_DIM;
    p.a2Zrow = CHK; p.b2Zrow = E_DIM;
    gemm_mfma<128,128,0,0,0,1,0,0,0,0,0,1,1,0,0><<<dim3(2,4,B_SZ*NCHK), blk, 0, stream>>>(p);
    // lat += t2b @ Wo^T
    clr(); p.A = t2b; p.B = wob + wOff; p.bias = bo + bOff; p.Cf = lat; p.nkt = 8;
    gemm_mfma<128,128,0,1,1,0,0,0,0,0,0,0,0,0,1><<<dim3(64,4), blk, 0, stream>>>(p);
    layernorm_k<<<dim3(ROWS / 4), blk, 0, stream>>>(lat, ln2g + bOff,
                                                    ln2b + bOff, h);
    // c1 (gelu) -> t2b ; lat += t2b @ c2^T
    clr(); p.A = h; p.B = wc1 + wOff; p.bias = c1b + bOff; p.Cb = t2b; p.nkt = 8;
    gemm_mfma<128,128,2,0,0,1,0,0,0,0,0,0,0,0,1><<<dim3(64,4), blk, 0, stream>>>(p);
    clr(); p.A = t2b; p.B = wc2 + wOff; p.bias = c2b + bOff; p.Cf = lat; p.nkt = 8;
    gemm_mfma<128,128,0,1,1,0,0,0,0,0,0,0,0,0,1><<<dim3(64,4), blk, 0, stream>>>(p);
  }
  out_proj<<<dim3(S_LEN / 64, 1, B_SZ), blk, 0, stream>>>(lat, oW, ob, out);
}

// Round 5
// 669.622 us; speedup vs baseline: 1.1745x; 1.1745x over previous
//
#include <hip/hip_runtime.h>
#include <hip/hip_bf16.h>
#include <cmath>

#define S_LEN 2048
#define E_DIM 512
#define B_SZ 4
#define CIN_D 64
#define COUT_D 64
#define L_NUM 4
#define CHK 256
#define NCHK 8
#define ROWS (B_SZ * S_LEN)  // 8192
#define PADR 2050            // padded rows per batch for causal conv
#define QLD 1024             // leading dim of fused qk buffer

typedef __attribute__((ext_vector_type(8))) short short8;
typedef __attribute__((ext_vector_type(4))) float f32x4;
typedef unsigned short ushort_t;

__device__ __forceinline__ ushort_t f2b(float v) {
  __hip_bfloat16 t = __float2bfloat16(v);
  return __builtin_bit_cast(ushort_t, t);
}
__device__ __forceinline__ float b2f(ushort_t u) {
  return __builtin_bit_cast(float, ((unsigned)u) << 16);
}
__device__ __forceinline__ float b2f(unsigned u) {
  return __builtin_bit_cast(float, u << 16);
}

__device__ __forceinline__ void gload16(const void* g, void* l) {
  __builtin_amdgcn_global_load_lds((const __attribute__((address_space(1))) void*)g,
                                   (__attribute__((address_space(3))) void*)l, 16, 0, 0);
}

__device__ __forceinline__ void barrier_mem() {
  asm volatile("s_barrier" ::: "memory");
}
template <int N>
__device__ __forceinline__ void waitn() {
  if constexpr (N == 0) asm volatile("s_waitcnt vmcnt(0)" ::: "memory");
  else if constexpr (N == 6) asm volatile("s_waitcnt vmcnt(6)" ::: "memory");
  else asm volatile("s_waitcnt vmcnt(8)" ::: "memory");
  __builtin_amdgcn_sched_barrier(0);
}

// ======================= universal bf16 MFMA GEMM =======================
// Tile TM x TN, BK=64, 4 waves (2x2), double-buffered LDS, counted-vmcnt
// 2-deep pipeline: stage(next) -> wait older tile -> bar -> compute -> bar.
struct GemmP {
  const ushort_t* A; const ushort_t* B; const float* bias;
  ushort_t* Cb; const float* den;
  int nkt, lda, ldb, ldc;
  int aZrow, aZcol, bZrow, bZcol, cZrow;
  const ushort_t* A2; const ushort_t* B2;
  int nkt2, lda2, ldb2, a2Zrow, b2Zrow;
};

template <int TM, int TN, bool CONV>
__device__ __forceinline__ void mma_phase(const ushort_t* A, const ushort_t* B,
                                          int nkt, int lda, int ldb, int arow0,
                                          int acol0, int brow0, int bcol0,
                                          char* sm, int tid,
                                          f32x4 (&acc)[TM / 32][TN / 32]) {
  constexpr int MF = TM / 32, NF = TN / 32;
  constexpr int ABY = TM * 128, BBY = TN * 128, BUF = ABY + BBY;
  constexpr int RA = ABY / 4096, RB = BBY / 4096;
  const int lane = tid & 63, w = tid >> 6;
  const int wr = (w >> 1) * (TM / 2), wc = (w & 1) * (TN / 2);
  const int l15 = lane & 15, l4 = lane >> 4;

  auto stage = [&](int kt, int buf) {
    int ar0 = arow0, ac0 = acol0 + (kt << 6);
    if (CONV) {
      ar0 = arow0 + (kt >> 3);
      ac0 = acol0 + ((kt & 7) << 6);
    }
    char* s = sm + buf * BUF;
#pragma unroll
    for (int r = 0; r < RA; ++r) {
      const int f = (r << 12) + (tid << 4);
      const int row = f >> 7, sw = ((((f >> 4) & 7)) ^ (row & 7)) << 3;
      gload16(A + (size_t)(ar0 + row) * lda + ac0 + sw, s + f);
    }
    const int bc0 = bcol0 + (kt << 6);
#pragma unroll
    for (int r = 0; r < RB; ++r) {
      const int f = (r << 12) + (tid << 4);
      const int row = f >> 7, sw = ((((f >> 4) & 7)) ^ (row & 7)) << 3;
      gload16(B + (size_t)(brow0 + row) * ldb + bc0 + sw, s + ABY + f);
    }
  };

  stage(0, 0);
  int cur = 0;
  for (int kt = 0; kt < nkt; ++kt) {
    if (kt + 1 < nkt) {
      stage(kt + 1, cur ^ 1);  // prefetch next tile (RA+RB loads per thread)
      waitn<RA + RB>();        // wait ONLY the older (current) tile
    } else {
      waitn<0>();
    }
    barrier_mem();  // all waves' staging of cur visible
    char* s = sm + cur * BUF;
#pragma unroll
    for (int kk = 0; kk < 2; ++kk) {
      short8 af[MF], bfv[NF];
#pragma unroll
      for (int m = 0; m < MF; ++m) {
        const int rt = wr + (m << 4) + l15;
        af[m] = *(const short8*)(s + rt * 128 +
                                 (((kk << 6) + (l4 << 4)) ^ ((rt & 7) << 4)));
      }
#pragma unroll
      for (int n = 0; n < NF; ++n) {
        const int rt = wc + (n << 4) + l15;
        bfv[n] = *(const short8*)(s + ABY + rt * 128 +
                                  (((kk << 6) + (l4 << 4)) ^ ((rt & 7) << 4)));
      }
#pragma unroll
      for (int m = 0; m < MF; ++m)
#pragma unroll
        for (int n = 0; n < NF; ++n)
          acc[m][n] = __builtin_amdgcn_mfma_f32_16x16x32_bf16(af[m], bfv[n],
                                                              acc[m][n], 0, 0, 0);
    }
    __builtin_amdgcn_sched_barrier(0);
    asm volatile("s_waitcnt lgkmcnt(0)" ::: "memory");  // ds_reads retired
    barrier_mem();  // readers done -> next stage may overwrite cur
    cur ^= 1;
  }
}

// ACT: 0 none, 1 phi, 2 gelu, 3 phi-if-row<512 (fused k|v)
template <int TM, int TN, int ACT, bool READC, bool PADA, bool PADC,
          bool BIASROW, bool TRIMASK, bool SKIPUP, bool DIVDEN, bool TWOPH,
          bool CONV, bool SWZ, bool HALFK>
__global__ __launch_bounds__(256) void gemm_mfma(GemmP p) {
  constexpr int MF = TM / 32, NF = TN / 32;
  __shared__ __align__(16) char smem[2 * (TM + TN) * 128];
  const int tid = threadIdx.x;
  int bxx = blockIdx.x, byy = blockIdx.y;
  if (SWZ) {  // XCD-aware chunked remap (nwg divisible by 8)
    const int gx = gridDim.x, gy = gridDim.y;
    const int hw = byy * gx + bxx;
    const int cpx = (gx * gy) >> 3;
    const int swz = (hw & 7) * cpx + (hw >> 3);
    if (gx >= gy) { bxx = swz / gy; byy = swz % gy; }
    else          { byy = swz / gx; bxx = swz % gx; }
  }
  const int bm = bxx * TM, bn = byy * TN, z = blockIdx.z;
  const int lane = tid & 63, w = tid >> 6;
  const int wr = (w >> 1) * (TM / 2), wc = (w & 1) * (TN / 2);
  const int l15 = lane & 15, l4 = lane >> 4;

  if (SKIPUP && bn >= bm + TM) {  // fully-masked tile: zero-fill Cb
#pragma unroll
    for (int m = 0; m < MF; ++m)
#pragma unroll
      for (int j = 0; j < 4; ++j) {
        const int rloc = bm + wr + (m << 4) + (l4 << 2) + j;
        const size_t crow = (size_t)p.cZrow * z + rloc;
#pragma unroll
        for (int n = 0; n < NF; ++n)
          p.Cb[crow * p.ldc + bn + wc + (n << 4) + l15] = 0;
      }
    return;
  }

  f32x4 acc[MF][NF];
#pragma unroll
  for (int m = 0; m < MF; ++m)
#pragma unroll
    for (int n = 0; n < NF; ++n)
#pragma unroll
      for (int j = 0; j < 4; ++j) acc[m][n][j] = 0.f;

  int arow0 = bm + p.aZrow * z;
  if (PADA) arow0 = bm + ((bm >> 11) << 1);  // padded batch base
  int nkt1 = p.nkt;
  if (HALFK) nkt1 = min(p.nkt, (bm + TM) >> 6);  // causal K truncation
  mma_phase<TM, TN, CONV>(p.A, p.B, nkt1, p.lda, p.ldb, arow0, p.aZcol * z,
                          bn + p.bZrow * z, p.bZcol * z, smem, tid, acc);
  if (TWOPH)
    mma_phase<TM, TN, false>(p.A2, p.B2, p.nkt2, p.lda2, p.ldb2,
                             bm + p.a2Zrow * z, 0, bn + p.b2Zrow * z, 0, smem,
                             tid, acc);

  float bcol[NF];
  if (p.bias && !BIASROW) {
#pragma unroll
    for (int n = 0; n < NF; ++n) bcol[n] = p.bias[bn + wc + (n << 4) + l15];
  }
  int crow_base = bm;
  if (PADC) crow_base = bm + ((bm >> 11) << 1) + 2;
#pragma unroll
  for (int m = 0; m < MF; ++m) {
#pragma unroll
    for (int j = 0; j < 4; ++j) {
      const int rloc = wr + (m << 4) + (l4 << 2) + j;
      const size_t crow = (size_t)p.cZrow * z + crow_base + rloc;
      float inv = 1.f;
      if (DIVDEN) inv = 1.f / (p.den[crow] + 1e-6f);
      float brbias = 0.f;
      if (BIASROW && p.bias) brbias = p.bias[bm + rloc];
#pragma unroll
      for (int n = 0; n < NF; ++n) {
        const int col = bn + wc + (n << 4) + l15;
        float v = acc[m][n][j];
        if (p.bias) v += BIASROW ? brbias : bcol[n];
        if (ACT == 1) v = v > 0.f ? v + 1.f : __expf(v);
        if (ACT == 2) v = 0.5f * v * (1.f + erff(v * 0.70710678118654752f));
        if (ACT == 3 && (bm + rloc) < 512) v = v > 0.f ? v + 1.f : __expf(v);
        if (TRIMASK) {
          if (col > bm + rloc) v = 0.f;
        }
        const size_t cidx = crow * p.ldc + col;
        if (READC) v += b2f(p.Cb[cidx]);  // residual add (bf16 stream)
        if (DIVDEN) v *= inv;
        p.Cb[cidx] = f2b(v);
      }
    }
  }
}

// ======================= prep / small kernels =======================

struct CvtP {
  const float *in_W, *cc_W, *Wq, *Wk, *Wv, *Wo, *c1W, *c2W, *bq, *bk, *bv;
  ushort_t *winb, *wconv, *wqkb, *wkvb, *wob, *wc1, *wc2;
  float *bqk, *bkv;
  ushort_t* t2pad;
};
__global__ void cvt_all(CvtP c) {
  const size_t NT = 32768 + 786432 + 2097152 * 2 + 1048576 * 3 + 4096 * 2 + 4096;
  for (size_t i = (size_t)blockIdx.x * 256 + threadIdx.x; i < NT;
       i += (size_t)gridDim.x * 256) {
    size_t j = i;
    if (j < 32768) { c.winb[j] = f2b(c.in_W[j]); continue; }
    j -= 32768;
    if (j < 786432) {  // wconv[n][tap*512+k] = cc_W[n][k][tap]
      size_t n = j / 1536, r = j % 1536;
      c.wconv[j] = f2b(c.cc_W[n * 1536 + (r & 511) * 3 + (r >> 9)]);
      continue;
    }
    j -= 786432;
    if (j < 2097152) {
      size_t l = j >> 19, r = j & 524287, row = r >> 9, k = r & 511;
      c.wqkb[j] = f2b(row < 512 ? c.Wq[l * 262144 + row * 512 + k]
                                : c.Wk[l * 262144 + (row - 512) * 512 + k]);
      continue;
    }
    j -= 2097152;
    if (j < 2097152) {
      size_t l = j >> 19, r = j & 524287, row = r >> 9, k = r & 511;
      c.wkvb[j] = f2b(row < 512 ? c.Wk[l * 262144 + row * 512 + k]
                                : c.Wv[l * 262144 + (row - 512) * 512 + k]);
      continue;
    }
    j -= 2097152;
    if (j < 1048576) { c.wob[j] = f2b(c.Wo[j]); continue; }
    j -= 1048576;
    if (j < 1048576) { c.wc1[j] = f2b(c.c1W[j]); continue; }
    j -= 1048576;
    if (j < 1048576) { c.wc2[j] = f2b(c.c2W[j]); continue; }
    j -= 1048576;
    if (j < 4096) {
      size_t l = j >> 10, r = j & 1023;
      c.bqk[j] = r < 512 ? c.bq[l * 512 + r] : c.bk[l * 512 + r - 512];
      continue;
    }
    j -= 4096;
    if (j < 4096) {
      size_t l = j >> 10, r = j & 1023;
      c.bkv[j] = r < 512 ? c.bk[l * 512 + r] : c.bv[l * 512 + r - 512];
      continue;
    }
    j -= 4096;
    {  // zero-fill the 2 pad rows at each batch start of t2pad
      int b = (int)(j >> 10), r = (int)(j & 1023);
      c.t2pad[(size_t)(b * PADR) * E_DIM + r] = 0;
    }
  }
}

__global__ __launch_bounds__(256) void transpose_x(const float* __restrict__ x,
                                                   ushort_t* __restrict__ xT) {
  __shared__ float t[64][65];
  const int b = blockIdx.z, s0 = blockIdx.x << 6, tid = threadIdx.x;
#pragma unroll
  for (int i = 0; i < 16; ++i) {
    int idx = tid + (i << 8);
    int c = idx >> 6, s = idx & 63;
    t[c][s] = x[(((size_t)(b * CIN_D + c)) << 11) + s0 + s];
  }
  __syncthreads();
#pragma unroll
  for (int i = 0; i < 16; ++i) {
    int idx = tid + (i << 8);
    int s = idx >> 6, c = idx & 63;
    xT[(((size_t)(b * S_LEN + s0 + s)) << 6) + c] = f2b(t[c][s]);
  }
}

// wave-per-row layernorm over bf16 latent: 4 rows / block
__global__ __launch_bounds__(256) void layernorm_b(const ushort_t* __restrict__ x,
                                                   const float* __restrict__ g,
                                                   const float* __restrict__ bb,
                                                   ushort_t* __restrict__ y) {
  const int wid = threadIdx.x >> 6, lane = threadIdx.x & 63;
  const int row = (blockIdx.x << 2) + wid;
  const ushort_t* xr = x + ((size_t)row << 9);
  const uint4 u = *(const uint4*)(xr + (lane << 3));  // 8 bf16
  float v[8];
  v[0] = b2f(u.x & 0xffffu); v[1] = b2f(u.x >> 16);
  v[2] = b2f(u.y & 0xffffu); v[3] = b2f(u.y >> 16);
  v[4] = b2f(u.z & 0xffffu); v[5] = b2f(u.z >> 16);
  v[6] = b2f(u.w & 0xffffu); v[7] = b2f(u.w >> 16);
  float s = 0.f, q2 = 0.f;
#pragma unroll
  for (int i = 0; i < 8; ++i) { s += v[i]; q2 += v[i] * v[i]; }
#pragma unroll
  for (int off = 32; off; off >>= 1) {
    s += __shfl_xor(s, off);
    q2 += __shfl_xor(q2, off);
  }
  const float m = s * (1.f / 512.f);
  const float r = rsqrtf(q2 * (1.f / 512.f) - m * m + 1e-5f);
  const int c = lane << 3;
  const float4 g0 = *(const float4*)(g + c);
  const float4 g1 = *(const float4*)(g + c + 4);
  const float4 b0 = *(const float4*)(bb + c);
  const float4 b1 = *(const float4*)(bb + c + 4);
  uint4 o;
  o.x = ((unsigned)f2b((v[1] - m) * r * g0.y + b0.y) << 16) |
        f2b((v[0] - m) * r * g0.x + b0.x);
  o.y = ((unsigned)f2b((v[3] - m) * r * g0.w + b0.w) << 16) |
        f2b((v[2] - m) * r * g0.z + b0.z);
  o.z = ((unsigned)f2b((v[5] - m) * r * g1.y + b1.y) << 16) |
        f2b((v[4] - m) * r * g1.x + b1.x);
  o.w = ((unsigned)f2b((v[7] - m) * r * g1.w + b1.w) << 16) |
        f2b((v[6] - m) * r * g1.z + b1.z);
  *(uint4*)(y + ((size_t)row << 9) + c) = o;
}

// ksum[z][e] = sum_t kT[e][z*256+t]; wave per (z,e), contiguous 8B loads
__global__ __launch_bounds__(256) void ksum_k(const ushort_t* __restrict__ kT,
                                              float* __restrict__ ks) {
  const int gw = (int)(((size_t)blockIdx.x << 8) + threadIdx.x) >> 6;
  const int lane = threadIdx.x & 63;
  const int z = gw >> 9, e = gw & 511;
  const uint2 u =
      *(const uint2*)(kT + (size_t)e * ROWS + (z << 8) + (lane << 2));
  float s = b2f(u.x & 0xffffu) + b2f(u.x >> 16) + b2f(u.y & 0xffffu) +
            b2f(u.y >> 16);
#pragma unroll
  for (int off = 32; off; off >>= 1) s += __shfl_xor(s, off);
  if (lane == 0) ks[(z << 9) + e] = s;
}

// merged: blocks 0..4095 = exclusive chunk prefix Pb->PTb (bf16, fp32 acc);
//         blocks 4096..6143 = den (wave per row, ks prefix inlined)
__global__ __launch_bounds__(256) void misc_k(
    const ushort_t* __restrict__ Pb, ushort_t* __restrict__ PTb,
    const ushort_t* __restrict__ Sc, const ushort_t* __restrict__ qk,
    const float* __restrict__ ksum, float* __restrict__ den) {
  int bid = blockIdx.x;
  if (bid < 4096) {
    const size_t idx = ((size_t)bid << 8) + threadIdx.x;  // < B*E*E
    const int b = (int)(idx >> 18);
    const size_t r = idx & ((1u << 18) - 1);
    float acc = 0.f;
#pragma unroll
    for (int j = 0; j < NCHK; ++j) {
      const size_t o = (((size_t)(b * NCHK + j)) << 18) + r;
      PTb[o] = f2b(acc);
      acc += b2f(Pb[o]);
    }
  } else {
    bid -= 4096;
    const int wid = threadIdx.x >> 6, lane = threadIdx.x & 63;
    const int row = (bid << 2) + wid;  // < 8192
    const int z = row >> 8, sl = row & 255;
    const ushort_t* sr = Sc + (((size_t)z) << 16) + ((size_t)sl << 8);
    float s = 0.f;
#pragma unroll
    for (int t = 0; t < 4; ++t) s += b2f(sr[lane + (t << 6)]);
    const ushort_t* qr = qk + (size_t)row * QLD;
    const int j0 = z & ~7;
    for (int e = lane; e < E_DIM; e += 64) {
      float kp = 0.f;
      for (int j = j0; j < z; ++j) kp += ksum[(j << 9) + e];
      s += b2f(qr[e]) * kp;
    }
#pragma unroll
    for (int off = 32; off; off >>= 1) s += __shfl_xor(s, off);
    if (lane == 0) den[row] = s;
  }
}

__global__ __launch_bounds__(256) void out_proj(const ushort_t* __restrict__ lat,
                                                const float* __restrict__ W,
                                                const float* __restrict__ bias,
                                                float* __restrict__ out) {
  const int b = blockIdx.z, bs = blockIdx.x << 6;
  const int tid = threadIdx.x, tm = tid >> 4, tn = tid & 15;
  const int lr = tid >> 2, lc = (tid & 3) << 2;
  __shared__ float As[16][64], Ws[16][64];
  float acc[4][4] = {{0.f}};
  for (int k0 = 0; k0 < E_DIM; k0 += 16) {
    const uint2 ra =
        *(const uint2*)(lat + (((size_t)(b * S_LEN + bs + lr)) << 9) + k0 + lc);
    As[lc + 0][lr] = b2f(ra.x & 0xffffu);
    As[lc + 1][lr] = b2f(ra.x >> 16);
    As[lc + 2][lr] = b2f(ra.y & 0xffffu);
    As[lc + 3][lr] = b2f(ra.y >> 16);
    float4 wv = *(const float4*)(W + (((size_t)lr) << 9) + k0 + lc);
    Ws[lc + 0][lr] = wv.x; Ws[lc + 1][lr] = wv.y;
    Ws[lc + 2][lr] = wv.z; Ws[lc + 3][lr] = wv.w;
    __syncthreads();
#pragma unroll
    for (int kk = 0; kk < 16; ++kk) {
      const float4 a4 = *(const float4*)&As[kk][tm << 2];
      const float4 b4 = *(const float4*)&Ws[kk][tn << 2];
      const float aa[4] = {a4.x, a4.y, a4.z, a4.w};
      const float bb[4] = {b4.x, b4.y, b4.z, b4.w};
#pragma unroll
      for (int i = 0; i < 4; ++i)
#pragma unroll
        for (int j2 = 0; j2 < 4; ++j2) acc[i][j2] += aa[i] * bb[j2];
    }
    __syncthreads();
  }
#pragma unroll
  for (int i = 0; i < 4; ++i)
#pragma unroll
    for (int j2 = 0; j2 < 4; ++j2) {
      const int o = (tn << 2) + j2, sl = bs + (tm << 2) + i;
      out[(((size_t)(b * COUT_D + o)) << 11) + sl] = acc[i][j2] + bias[o];
    }
}

// ======================= host launcher =======================
extern "C" void kernel_launch(void* const* d_in, const int* in_sizes, int n_in,
                              void* d_out, int out_size, void* d_ws,
                              size_t ws_size, hipStream_t stream) {
  const float* x = (const float*)d_in[0];
  const float* in_W = (const float*)d_in[1];
  const float* in_b = (const float*)d_in[2];
  const float* cc_W = (const float*)d_in[3];
  const float* cc_b = (const float*)d_in[4];
  const float* ln1g = (const float*)d_in[5];
  const float* ln1b = (const float*)d_in[6];
  const float* ln2g = (const float*)d_in[7];
  const float* ln2b = (const float*)d_in[8];
  const float* Wq = (const float*)d_in[9];
  const float* bq = (const float*)d_in[10];
  const float* Wk = (const float*)d_in[11];
  const float* bk = (const float*)d_in[12];
  const float* Wv = (const float*)d_in[13];
  const float* bv = (const float*)d_in[14];
  const float* Wo = (const float*)d_in[15];
  const float* bo = (const float*)d_in[16];
  const float* c1W = (const float*)d_in[17];
  const float* c1b = (const float*)d_in[18];
  const float* c2W = (const float*)d_in[19];
  const float* c2b = (const float*)d_in[20];
  const float* oW = (const float*)d_in[21];
  const float* ob = (const float*)d_in[22];
  float* out = (float*)d_out;

  const size_t NE = (size_t)ROWS * E_DIM;  // 4194304
  float* ks = (float*)d_ws;  // 16384
  float* den = ks + 16384;   // 8192
  float* bqk = den + 8192;   // 4096
  float* bkv = bqk + 4096;   // 4096
  ushort_t* u = (ushort_t*)(bkv + 4096);
  ushort_t* latb = u;   u += NE;
  ushort_t* Pb = u;     u += 8388608;
  ushort_t* xT = u;     u += (size_t)ROWS * CIN_D;
  ushort_t* t2pad = u;  u += (size_t)B_SZ * PADR * E_DIM;
  ushort_t* h = u;      u += NE;
  ushort_t* qk = u;     u += (size_t)ROWS * QLD;
  ushort_t* kvT = u;    u += (size_t)1024 * ROWS;
  ushort_t* PTb = u;    u += 8388608;
  ushort_t* t2b = u;    u += NE;
  ushort_t* winb = u;   u += 32768;
  ushort_t* wconv = u;  u += 786432;
  ushort_t* wqkb = u;   u += 2097152;
  ushort_t* wkvb = u;   u += 2097152;
  ushort_t* wob = u;    u += 1048576;
  ushort_t* wc1 = u;    u += 1048576;
  ushort_t* wc2 = u;    u += 1048576;
  ushort_t* Sc = t2pad;  // alias: t2pad dead after conv; 2M <= 4.2M elems
  ushort_t* kT = kvT;    // rows 0..511
  ushort_t* vT = kvT + (size_t)512 * ROWS;

  const dim3 blk(256);

  CvtP cp{in_W, cc_W, Wq, Wk, Wv, Wo, c1W, c2W, bq, bk, bv,
          winb, wconv, wqkb, wkvb, wob, wc1, wc2, bqk, bkv, t2pad};
  cvt_all<<<dim3(4096), blk, 0, stream>>>(cp);
  transpose_x<<<dim3(S_LEN / 64, 1, B_SZ), blk, 0, stream>>>(x, xT);

  GemmP p;
  auto clr = [&]() {
    p = GemmP{};
    p.lda = E_DIM; p.ldb = E_DIM; p.ldc = E_DIM;
  };

  // template args: TM,TN,ACT,READC,PADA,PADC,BIASROW,TRIMASK,SKIPUP,DIVDEN,
  //                TWOPH,CONV,SWZ,HALFK
  // input projection -> padded bf16 latent (K=64)
  clr(); p.A = xT; p.B = winb; p.bias = in_b; p.Cb = t2pad;
  p.nkt = 1; p.lda = 64; p.ldb = 64;
  gemm_mfma<128,128,0,0,0,1,0,0,0,0,0,0,1,0><<<dim3(64,4), blk, 0, stream>>>(p);
  // fused causal conv: one GEMM, K=1536 (3 taps x 512) -> latb (bf16)
  clr(); p.A = t2pad; p.B = wconv; p.bias = cc_b; p.Cb = latb;
  p.nkt = 24; p.ldb = 1536;
  gemm_mfma<128,128,0,0,1,0,0,0,0,0,0,1,1,0><<<dim3(64,4), blk, 0, stream>>>(p);

  for (int i = 0; i < L_NUM; ++i) {
    const size_t wOff = (size_t)i * E_DIM * E_DIM;
    const size_t bOff = (size_t)i * E_DIM;
    layernorm_b<<<dim3(ROWS / 4), blk, 0, stream>>>(latb, ln1g + bOff,
                                                    ln1b + bOff, h);
    // fused q|k (phi on both): [8192 x 1024]
    clr(); p.A = h; p.B = wqkb + (size_t)i * 524288; p.bias = bqk + i * 1024;
    p.Cb = qk; p.nkt = 8; p.ldc = QLD;
    gemm_mfma<128,128,1,0,0,0,0,0,0,0,0,0,1,0><<<dim3(64,8), blk, 0, stream>>>(p);
    // fused kT|vT (phi on k rows only): [1024 x 8192]
    clr(); p.A = wkvb + (size_t)i * 524288; p.B = h; p.bias = bkv + i * 1024;
    p.Cb = kvT; p.nkt = 8; p.ldc = ROWS;
    gemm_mfma<128,128,3,0,0,0,1,0,0,0,0,0,1,0><<<dim3(8,64), blk, 0, stream>>>(p);
    ksum_k<<<dim3(4096), blk, 0, stream>>>(kT, ks);
    // per-chunk PT[e'][e] = sum_t vT[e',t] kT[e,t] -> Pb (bf16)
    clr(); p.A = vT; p.B = kT; p.Cb = Pb; p.nkt = 4;
    p.lda = ROWS; p.ldb = ROWS; p.aZcol = CHK; p.bZcol = CHK; p.cZrow = E_DIM;
    gemm_mfma<128,128,0,0,0,0,0,0,0,0,0,0,0,0><<<dim3(4,4,B_SZ*NCHK), blk, 0, stream>>>(p);
    // intra-chunk masked scores -> Sc (bf16, aliased onto t2pad)
    clr(); p.A = qk; p.B = qk + 512; p.Cb = Sc; p.nkt = 8;
    p.lda = QLD; p.ldb = QLD; p.ldc = CHK;
    p.aZrow = CHK; p.bZrow = CHK; p.cZrow = CHK;
    gemm_mfma<128,64,0,0,0,0,0,1,1,0,0,0,0,0><<<dim3(2,4,B_SZ*NCHK), blk, 0, stream>>>(p);
    // merged: prefix (Pb->PTb) || den (rowsum(Sc) + q . inline-ks-prefix)
    misc_k<<<dim3(6144), blk, 0, stream>>>(Pb, PTb, Sc, qk, ks, den);
    // combine: (Sc@vT + q@PTb) / den -> t2b (bf16); causal K-trunc on Sc phase
    clr(); p.A = Sc; p.B = vT; p.Cb = t2b; p.den = den;
    p.nkt = 4; p.lda = CHK; p.ldb = ROWS; p.aZrow = CHK; p.bZcol = CHK; p.cZrow = CHK;
    p.A2 = qk; p.B2 = PTb; p.nkt2 = 8; p.lda2 = QLD; p.ldb2 = E_DIM;
    p.a2Zrow = CHK; p.b2Zrow = E_DIM;
    gemm_mfma<64,128,0,0,0,0,0,0,0,1,1,0,0,1><<<dim3(4,4,B_SZ*NCHK), blk, 0, stream>>>(p);
    // latb += t2b @ Wo^T  (bf16 residual RMW)
    clr(); p.A = t2b; p.B = wob + wOff; p.bias = bo + bOff; p.Cb = latb; p.nkt = 8;
    gemm_mfma<64,128,0,1,0,0,0,0,0,0,0,0,1,0><<<dim3(128,4), blk, 0, stream>>>(p);
    layernorm_b<<<dim3(ROWS / 4), blk, 0, stream>>>(latb, ln2g + bOff,
                                                    ln2b + bOff, h);
    // c1 (gelu) -> t2b ; latb += t2b @ c2^T
    clr(); p.A = h; p.B = wc1 + wOff; p.bias = c1b + bOff; p.Cb = t2b; p.nkt = 8;
    gemm_mfma<64,128,2,0,0,0,0,0,0,0,0,0,1,0><<<dim3(128,4), blk, 0, stream>>>(p);
    clr(); p.A = t2b; p.B = wc2 + wOff; p.bias = c2b + bOff; p.Cb = latb; p.nkt = 8;
    gemm_mfma<64,128,0,1,0,0,0,0,0,0,0,0,1,0><<<dim3(128,4), blk, 0, stream>>>(p);
  }
  out_proj<<<dim3(S_LEN / 64, 1, B_SZ), blk, 0, stream>>>(latb, oW, ob, out);
}